// Round 1
// baseline (40.675 us; speedup 1.0000x reference)
//
#include <hip/hip_runtime.h>
#include <math.h>

#define DHID   784
#define HID    1024
#define NB     10
#define MC_LD  800                         // padded leading dim for Mc rows
#define M2_OFF (11*MC_LD)                  // 8800
#define M2_LD  12
#define C0_OFF (M2_OFF + 64*M2_LD)         // 9568
#define WS_FLOATS 9600                     // 2400 float4
#define DELTA0 7.0f

// ---------------------------------------------------------------------------
// prep: fold all weights.
// ws layout (floats):
//   [0 .. 8800)   Mc[11][800]: c<10 -> column c of M1 = W_in @ (g .* W_out)
//                              c==10 -> w_mean[d] = (1/1024) * sum_j W_in[d][j]
//   [8800..9568)  M2[64][12] : M2[h][c] = sum_j W_ph[h][j]*g[j]*W_out[j][c]
//   [9568..9578)  c0[10] = (b_in+b_ph)*g @ W_out + b_out
//   [9578]        bmean = mean(b_in)
// g[j] = 2 if j<5 else 1  (the spiking-attention gains are provably constant:
// every top-k token spikes exactly once and resets to 0, so V ends all-zero
// and top_k(V,5) -> indices 0..4).
// ---------------------------------------------------------------------------
__global__ void prep_kernel(const float* __restrict__ W_in,
                            const float* __restrict__ b_in,
                            const float* __restrict__ W_ph,
                            const float* __restrict__ b_ph,
                            const float* __restrict__ W_out,
                            const float* __restrict__ b_out,
                            float* __restrict__ ws) {
  const int b = blockIdx.x;      // 0..783: W_in row; 784..847: W_ph row; 848: bias
  const int l = threadIdx.x;     // 64 threads

  float acc[11];
#pragma unroll
  for (int c = 0; c < 11; ++c) acc[c] = 0.f;

  for (int j = l; j < HID; j += 64) {
    float w, extra;
    if (b < DHID)            { w = W_in[b*HID + j];          extra = w;       }
    else if (b < DHID + 64)  { w = W_ph[(b - DHID)*HID + j]; extra = 0.f;     }
    else                     { w = b_in[j] + b_ph[j];        extra = b_in[j]; }
    const float wg = (j < 5) ? 2.0f * w : w;
    const float2* wrow = (const float2*)(W_out + (size_t)j * NB);  // 8B aligned
#pragma unroll
    for (int p = 0; p < 5; ++p) {
      float2 w2 = wrow[p];
      acc[2*p]     += wg * w2.x;
      acc[2*p + 1] += wg * w2.y;
    }
    acc[10] += extra;
  }

#pragma unroll
  for (int c = 0; c < 11; ++c) {
    float v = acc[c];
    v += __shfl_xor(v, 1,  64);
    v += __shfl_xor(v, 2,  64);
    v += __shfl_xor(v, 4,  64);
    v += __shfl_xor(v, 8,  64);
    v += __shfl_xor(v, 16, 64);
    v += __shfl_xor(v, 32, 64);
    acc[c] = v;
  }

  if (l == 0) {
    if (b < DHID) {
#pragma unroll
      for (int c = 0; c < 10; ++c) ws[c*MC_LD + b] = acc[c];
      ws[10*MC_LD + b] = acc[10] * (1.0f / HID);
    } else if (b < DHID + 64) {
      const int h = b - DHID;
#pragma unroll
      for (int c = 0; c < 10; ++c) ws[M2_OFF + h*M2_LD + c] = acc[c];
      ws[M2_OFF + h*M2_LD + 10] = 0.f;
      ws[M2_OFF + h*M2_LD + 11] = 0.f;
    } else {
#pragma unroll
      for (int c = 0; c < 10; ++c) ws[C0_OFF + c] = acc[c] + b_out[c];
      ws[C0_OFF + 10] = acc[10] * (1.0f / HID);
    }
  }
}

// ---------------------------------------------------------------------------
// main: out[r][c] = x[r]·M1[:,c] + T(m_r)·M2[:,c] + c0[c],  m_r = x[r]·w_mean+bmean
// wave = 16 k-lanes x 4 subgroups, 2 rows per lane -> 8 rows/wave, 32 rows/block
// ---------------------------------------------------------------------------
__device__ __forceinline__ void row_tail(int row, const float* a,
                                         const float* lds, float* out,
                                         int kl, float bmean) {
  const float m    = a[10] + bmean;
  const float base = DELTA0 * m;
  float s1, c1, s2, c2;
  __sincosf((float)(kl + 1)  * base, &s1, &c1);   // harmonic kl+1
  __sincosf((float)(kl + 17) * base, &s2, &c2);   // harmonic kl+17
  const float* m2a = &lds[M2_OFF + (kl)      * M2_LD];  // cos, h=kl
  const float* m2b = &lds[M2_OFF + (kl + 16) * M2_LD];  // cos, h=kl+16
  const float* m2c = &lds[M2_OFF + (kl + 32) * M2_LD];  // sin, h=kl+32
  const float* m2d = &lds[M2_OFF + (kl + 48) * M2_LD];  // sin, h=kl+48
  float t[10];
#pragma unroll
  for (int c = 0; c < 10; ++c)
    t[c] = c1 * m2a[c] + c2 * m2b[c] + s1 * m2c[c] + s2 * m2d[c];
#pragma unroll
  for (int c = 0; c < 10; ++c) {
    float v = t[c];
    v += __shfl_xor(v, 1, 64);
    v += __shfl_xor(v, 2, 64);
    v += __shfl_xor(v, 4, 64);
    v += __shfl_xor(v, 8, 64);
    t[c] = v;
  }
  if (kl == 0) {
#pragma unroll
    for (int c = 0; c < 10; ++c)
      out[row * NB + c] = a[c] + t[c] + lds[C0_OFF + c];
  }
}

__global__ __launch_bounds__(256) void main_kernel(const float* __restrict__ x,
                                                   const float* __restrict__ ws,
                                                   float* __restrict__ out) {
  __shared__ float lds[WS_FLOATS];
  const int tid = threadIdx.x;

  // stage folded weights (38.4 KB) into LDS
  for (int idx = tid; idx < WS_FLOATS / 4; idx += 256)
    ((float4*)lds)[idx] = ((const float4*)ws)[idx];
  __syncthreads();

  const int wav  = tid >> 6;
  const int lane = tid & 63;
  const int kl   = lane & 15;
  const int rsub = lane >> 4;
  const int row  = blockIdx.x * 32 + wav * 8 + rsub * 2;   // this lane's row pair
  const float* x0 = x + (size_t)row * DHID;

  float a0[11], a1[11];
#pragma unroll
  for (int c = 0; c < 11; ++c) { a0[c] = 0.f; a1[c] = 0.f; }

#pragma unroll
  for (int i = 0; i < 13; ++i) {
    const int d = 4 * kl + 64 * i;
    if (d < DHID) {
      const float4 xa = *(const float4*)(x0 + d);
      const float4 xb = *(const float4*)(x0 + DHID + d);
#pragma unroll
      for (int c = 0; c < 11; ++c) {
        const float4 mv = *(const float4*)(&lds[c * MC_LD + d]);
        a0[c] += xa.x * mv.x + xa.y * mv.y + xa.z * mv.z + xa.w * mv.w;
        a1[c] += xb.x * mv.x + xb.y * mv.y + xb.z * mv.z + xb.w * mv.w;
      }
    }
  }

  // reduce partial dots across the 16 k-lanes (stays inside each 16-group)
#pragma unroll
  for (int c = 0; c < 11; ++c) {
    float v = a0[c];
    v += __shfl_xor(v, 1, 64);
    v += __shfl_xor(v, 2, 64);
    v += __shfl_xor(v, 4, 64);
    v += __shfl_xor(v, 8, 64);
    a0[c] = v;
    float u = a1[c];
    u += __shfl_xor(u, 1, 64);
    u += __shfl_xor(u, 2, 64);
    u += __shfl_xor(u, 4, 64);
    u += __shfl_xor(u, 8, 64);
    a1[c] = u;
  }

  const float bmean = lds[C0_OFF + 10];
  row_tail(row,     a0, lds, out, kl, bmean);
  row_tail(row + 1, a1, lds, out, kl, bmean);
}

// ---------------------------------------------------------------------------
extern "C" void kernel_launch(void* const* d_in, const int* in_sizes, int n_in,
                              void* d_out, int out_size, void* d_ws, size_t ws_size,
                              hipStream_t stream) {
  const float* x     = (const float*)d_in[0];
  const float* W_in  = (const float*)d_in[1];
  const float* b_in  = (const float*)d_in[2];
  const float* W_ph  = (const float*)d_in[3];
  const float* b_ph  = (const float*)d_in[4];
  const float* W_out = (const float*)d_in[5];
  const float* b_out = (const float*)d_in[6];
  float* out = (float*)d_out;
  float* ws  = (float*)d_ws;

  prep_kernel<<<DHID + 64 + 1, 64, 0, stream>>>(W_in, b_in, W_ph, b_ph,
                                                W_out, b_out, ws);
  main_kernel<<<512, 256, 0, stream>>>(x, ws, out);
}

// Round 2
// 39.850 us; speedup vs baseline: 1.0207x; 1.0207x over previous
//
#include <hip/hip_runtime.h>
#include <math.h>

#define DHID   784
#define HID    1024
#define NB     10
#define MC_LD  800                         // padded leading dim for Mc rows
#define M2_OFF (11*MC_LD)                  // 8800
#define M2_LD  13                          // gcd(13,32)=1 -> conflict-free
#define C0_OFF (M2_OFF + 64*M2_LD)         // 9632
#define WS_FLOATS 9648                     // 2412 float4
#define DELTA0 7.0f

// ---------------------------------------------------------------------------
// prep: fold all weights.
// ws layout (floats):
//   [0 .. 8800)   Mc[11][800]: c<10 -> column c of M1 = W_in @ (g .* W_out)
//                              c==10 -> w_mean[d] = (1/1024) * sum_j W_in[d][j]
//   [8800..9632)  M2[64][13] : M2[h][c] = sum_j W_ph[h][j]*g[j]*W_out[j][c]
//   [9632..9642)  c0[10] = (b_in+b_ph)*g @ W_out + b_out
//   [9642]        bmean = mean(b_in)
// g[j] = 2 if j<5 else 1  (spiking gains are provably constant: each top-k
// token spikes once and resets to 0, so V ends all-zero and top_k -> 0..4).
//
// 4 b-rows per block (one per wave); W_out staged in LDS padded to stride 11.
// ---------------------------------------------------------------------------
__global__ __launch_bounds__(256) void prep_kernel(
    const float* __restrict__ W_in,  const float* __restrict__ b_in,
    const float* __restrict__ W_ph,  const float* __restrict__ b_ph,
    const float* __restrict__ W_out, const float* __restrict__ b_out,
    float* __restrict__ ws) {
  __shared__ float wlds[HID * 11];           // 44 KB
  const int tid = threadIdx.x;

  for (int idx = tid; idx < HID * NB; idx += 256) {
    const int j = idx / NB;
    const int c = idx - j * NB;
    wlds[j * 11 + c] = W_out[idx];
  }
  __syncthreads();

  const int w = tid >> 6;
  const int l = tid & 63;
  const int b = blockIdx.x * 4 + w;          // 0..783 W_in row; 784..847 W_ph; 848 bias
  if (b > DHID + 64) return;

  float acc[11];
#pragma unroll
  for (int c = 0; c < 11; ++c) acc[c] = 0.f;

#pragma unroll 4
  for (int it = 0; it < 16; ++it) {
    const int j = l + 64 * it;
    float wv, extra;
    if (b < DHID)           { wv = W_in[b * HID + j];          extra = wv;      }
    else if (b < DHID + 64) { wv = W_ph[(b - DHID) * HID + j]; extra = 0.f;     }
    else                    { wv = b_in[j] + b_ph[j];          extra = b_in[j]; }
    const float wg = (j < 5) ? 2.0f * wv : wv;
    const float* wr = &wlds[j * 11];
#pragma unroll
    for (int c = 0; c < 10; ++c) acc[c] += wg * wr[c];
    acc[10] += extra;
  }

#pragma unroll
  for (int c = 0; c < 11; ++c) {
    float v = acc[c];
    v += __shfl_xor(v, 1,  64);
    v += __shfl_xor(v, 2,  64);
    v += __shfl_xor(v, 4,  64);
    v += __shfl_xor(v, 8,  64);
    v += __shfl_xor(v, 16, 64);
    v += __shfl_xor(v, 32, 64);
    acc[c] = v;
  }

  if (l == 0) {
    if (b < DHID) {
#pragma unroll
      for (int c = 0; c < 10; ++c) ws[c * MC_LD + b] = acc[c];
      ws[10 * MC_LD + b] = acc[10] * (1.0f / HID);
    } else if (b < DHID + 64) {
      const int h = b - DHID;
#pragma unroll
      for (int c = 0; c < 10; ++c) ws[M2_OFF + h * M2_LD + c] = acc[c];
      ws[M2_OFF + h * M2_LD + 10] = 0.f;
      ws[M2_OFF + h * M2_LD + 11] = 0.f;
      ws[M2_OFF + h * M2_LD + 12] = 0.f;
    } else {
#pragma unroll
      for (int c = 0; c < 10; ++c) ws[C0_OFF + c] = acc[c] + b_out[c];
      ws[C0_OFF + 10] = acc[10] * (1.0f / HID);
    }
  }
}

// ---------------------------------------------------------------------------
// main: out[r][c] = x[r]·M1[:,c] + T(m_r)·M2[:,c] + c0[c],  m_r = x[r]·w_mean+bmean
// wave = 16 k-lanes x 4 subgroups x 4 rows/lane -> 16 rows/wave, 64 rows/block,
// 256 blocks. LDS b128 reads amortized over 4 rows (vs 2 last round).
// ---------------------------------------------------------------------------
__device__ __forceinline__ void row_tail(int row, const float* a,
                                         const float* lds, float* out,
                                         int kl, float bmean) {
  const float m    = a[10] + bmean;
  const float base = DELTA0 * m;
  float s1, c1, s2, c2;
  __sincosf((float)(kl + 1)  * base, &s1, &c1);   // harmonic kl+1
  __sincosf((float)(kl + 17) * base, &s2, &c2);   // harmonic kl+17
  const float* m2a = &lds[M2_OFF + (kl)      * M2_LD];  // cos, h=kl
  const float* m2b = &lds[M2_OFF + (kl + 16) * M2_LD];  // cos, h=kl+16
  const float* m2c = &lds[M2_OFF + (kl + 32) * M2_LD];  // sin, h=kl+32
  const float* m2d = &lds[M2_OFF + (kl + 48) * M2_LD];  // sin, h=kl+48
  float t[10];
#pragma unroll
  for (int c = 0; c < 10; ++c)
    t[c] = c1 * m2a[c] + c2 * m2b[c] + s1 * m2c[c] + s2 * m2d[c];
#pragma unroll
  for (int c = 0; c < 10; ++c) {
    float v = t[c];
    v += __shfl_xor(v, 1, 64);
    v += __shfl_xor(v, 2, 64);
    v += __shfl_xor(v, 4, 64);
    v += __shfl_xor(v, 8, 64);
    t[c] = v;
  }
  if (kl == 0) {
#pragma unroll
    for (int c = 0; c < 10; ++c)
      out[row * NB + c] = a[c] + t[c] + lds[C0_OFF + c];
  }
}

__global__ __launch_bounds__(256) void main_kernel(const float* __restrict__ x,
                                                   const float* __restrict__ ws,
                                                   float* __restrict__ out) {
  __shared__ float lds[WS_FLOATS];
  const int tid = threadIdx.x;

  // stage folded weights (37.7 KB) into LDS
  for (int idx = tid; idx < WS_FLOATS / 4; idx += 256)
    ((float4*)lds)[idx] = ((const float4*)ws)[idx];
  __syncthreads();

  const int wav  = tid >> 6;
  const int lane = tid & 63;
  const int kl   = lane & 15;
  const int rsub = lane >> 4;
  const int row  = blockIdx.x * 64 + wav * 16 + rsub * 4;  // 4 rows per lane
  const float* x0 = x + (size_t)row * DHID;

  float a0[11], a1[11], a2[11], a3[11];
#pragma unroll
  for (int c = 0; c < 11; ++c) { a0[c] = 0.f; a1[c] = 0.f; a2[c] = 0.f; a3[c] = 0.f; }

#pragma unroll 6
  for (int i = 0; i < 12; ++i) {
    const int d = 4 * kl + 64 * i;
    const float4 xa = *(const float4*)(x0 + d);
    const float4 xb = *(const float4*)(x0 + DHID + d);
    const float4 xc = *(const float4*)(x0 + 2 * DHID + d);
    const float4 xd = *(const float4*)(x0 + 3 * DHID + d);
#pragma unroll
    for (int c = 0; c < 11; ++c) {
      const float4 mv = *(const float4*)(&lds[c * MC_LD + d]);
      a0[c] += xa.x * mv.x + xa.y * mv.y + xa.z * mv.z + xa.w * mv.w;
      a1[c] += xb.x * mv.x + xb.y * mv.y + xb.z * mv.z + xb.w * mv.w;
      a2[c] += xc.x * mv.x + xc.y * mv.y + xc.z * mv.z + xc.w * mv.w;
      a3[c] += xd.x * mv.x + xd.y * mv.y + xd.z * mv.z + xd.w * mv.w;
    }
  }
  // tail: d = 768 + 4*kl, valid only for kl < 4 (784 total)
  if (kl < 4) {
    const int d = 768 + 4 * kl;
    const float4 xa = *(const float4*)(x0 + d);
    const float4 xb = *(const float4*)(x0 + DHID + d);
    const float4 xc = *(const float4*)(x0 + 2 * DHID + d);
    const float4 xd = *(const float4*)(x0 + 3 * DHID + d);
#pragma unroll
    for (int c = 0; c < 11; ++c) {
      const float4 mv = *(const float4*)(&lds[c * MC_LD + d]);
      a0[c] += xa.x * mv.x + xa.y * mv.y + xa.z * mv.z + xa.w * mv.w;
      a1[c] += xb.x * mv.x + xb.y * mv.y + xb.z * mv.z + xb.w * mv.w;
      a2[c] += xc.x * mv.x + xc.y * mv.y + xc.z * mv.z + xc.w * mv.w;
      a3[c] += xd.x * mv.x + xd.y * mv.y + xd.z * mv.z + xd.w * mv.w;
    }
  }

  // reduce partial dots across the 16 k-lanes (stays inside each 16-group)
#pragma unroll
  for (int c = 0; c < 11; ++c) {
    float v;
    v = a0[c]; v += __shfl_xor(v,1,64); v += __shfl_xor(v,2,64);
    v += __shfl_xor(v,4,64); v += __shfl_xor(v,8,64); a0[c] = v;
    v = a1[c]; v += __shfl_xor(v,1,64); v += __shfl_xor(v,2,64);
    v += __shfl_xor(v,4,64); v += __shfl_xor(v,8,64); a1[c] = v;
    v = a2[c]; v += __shfl_xor(v,1,64); v += __shfl_xor(v,2,64);
    v += __shfl_xor(v,4,64); v += __shfl_xor(v,8,64); a2[c] = v;
    v = a3[c]; v += __shfl_xor(v,1,64); v += __shfl_xor(v,2,64);
    v += __shfl_xor(v,4,64); v += __shfl_xor(v,8,64); a3[c] = v;
  }

  const float bmean = lds[C0_OFF + 10];
  row_tail(row,     a0, lds, out, kl, bmean);
  row_tail(row + 1, a1, lds, out, kl, bmean);
  row_tail(row + 2, a2, lds, out, kl, bmean);
  row_tail(row + 3, a3, lds, out, kl, bmean);
}

// ---------------------------------------------------------------------------
extern "C" void kernel_launch(void* const* d_in, const int* in_sizes, int n_in,
                              void* d_out, int out_size, void* d_ws, size_t ws_size,
                              hipStream_t stream) {
  const float* x     = (const float*)d_in[0];
  const float* W_in  = (const float*)d_in[1];
  const float* b_in  = (const float*)d_in[2];
  const float* W_ph  = (const float*)d_in[3];
  const float* b_ph  = (const float*)d_in[4];
  const float* W_out = (const float*)d_in[5];
  const float* b_out = (const float*)d_in[6];
  float* out = (float*)d_out;
  float* ws  = (float*)d_ws;

  prep_kernel<<<(DHID + 64 + 1 + 3) / 4, 256, 0, stream>>>(W_in, b_in, W_ph, b_ph,
                                                           W_out, b_out, ws);
  main_kernel<<<256, 256, 0, stream>>>(x, ws, out);
}

// Round 3
// 38.031 us; speedup vs baseline: 1.0695x; 1.0478x over previous
//
#include <hip/hip_runtime.h>
#include <math.h>

#define DHID   784
#define HID    1024
#define NB     10
#define MC_LD  800                         // padded leading dim for Mc rows
#define M2_OFF (11*MC_LD)                  // 8800
#define M2_LD  13
#define C0_OFF (M2_OFF + 64*M2_LD)         // 9632
#define WS_FLOATS 9648
#define DELTA0 7.0f

// ---------------------------------------------------------------------------
// prep: fold all weights (unchanged from round 2 — fast, correct).
// ws layout (floats):
//   [0 .. 8800)   Mc[11][800]: c<10 -> column c of M1 = W_in @ (g .* W_out)
//                              c==10 -> w_mean[d] = (1/1024) * sum_j W_in[d][j]
//   [8800..9632)  M2[64][13] : M2[h][c] = sum_j W_ph[h][j]*g[j]*W_out[j][c]
//   [9632..9642)  c0[10] = (b_in+b_ph)*g @ W_out + b_out
//   [9642]        bmean = mean(b_in)
// g[j] = 2 if j<5 else 1  (spiking gains provably constant: each top-k token
// spikes once and resets to 0, so V ends all-zero and top_k -> indices 0..4).
// ---------------------------------------------------------------------------
__global__ __launch_bounds__(256) void prep_kernel(
    const float* __restrict__ W_in,  const float* __restrict__ b_in,
    const float* __restrict__ W_ph,  const float* __restrict__ b_ph,
    const float* __restrict__ W_out, const float* __restrict__ b_out,
    float* __restrict__ ws) {
  __shared__ float wlds[HID * 11];           // 44 KB
  const int tid = threadIdx.x;

  for (int idx = tid; idx < HID * NB; idx += 256) {
    const int j = idx / NB;
    const int c = idx - j * NB;
    wlds[j * 11 + c] = W_out[idx];
  }
  __syncthreads();

  const int w = tid >> 6;
  const int l = tid & 63;
  const int b = blockIdx.x * 4 + w;          // 0..783 W_in; 784..847 W_ph; 848 bias
  if (b > DHID + 64) return;

  float acc[11];
#pragma unroll
  for (int c = 0; c < 11; ++c) acc[c] = 0.f;

#pragma unroll 4
  for (int it = 0; it < 16; ++it) {
    const int j = l + 64 * it;
    float wv, extra;
    if (b < DHID)           { wv = W_in[b * HID + j];          extra = wv;      }
    else if (b < DHID + 64) { wv = W_ph[(b - DHID) * HID + j]; extra = 0.f;     }
    else                    { wv = b_in[j] + b_ph[j];          extra = b_in[j]; }
    const float wg = (j < 5) ? 2.0f * wv : wv;
    const float* wr = &wlds[j * 11];
#pragma unroll
    for (int c = 0; c < 10; ++c) acc[c] += wg * wr[c];
    acc[10] += extra;
  }

#pragma unroll
  for (int c = 0; c < 11; ++c) {
    float v = acc[c];
    v += __shfl_xor(v, 1,  64);
    v += __shfl_xor(v, 2,  64);
    v += __shfl_xor(v, 4,  64);
    v += __shfl_xor(v, 8,  64);
    v += __shfl_xor(v, 16, 64);
    v += __shfl_xor(v, 32, 64);
    acc[c] = v;
  }

  if (l == 0) {
    if (b < DHID) {
#pragma unroll
      for (int c = 0; c < 10; ++c) ws[c * MC_LD + b] = acc[c];
      ws[10 * MC_LD + b] = acc[10] * (1.0f / HID);
    } else if (b < DHID + 64) {
      const int h = b - DHID;
#pragma unroll
      for (int c = 0; c < 10; ++c) ws[M2_OFF + h * M2_LD + c] = acc[c];
      ws[M2_OFF + h * M2_LD + 10] = 0.f;
      ws[M2_OFF + h * M2_LD + 11] = 0.f;
      ws[M2_OFF + h * M2_LD + 12] = 0.f;
    } else {
#pragma unroll
      for (int c = 0; c < 10; ++c) ws[C0_OFF + c] = acc[c] + b_out[c];
      ws[C0_OFF + 10] = acc[10] * (1.0f / HID);
    }
  }
}

// ---------------------------------------------------------------------------
// main v3: NO LDS, no staging, no __syncthreads. Mc/M2/c0 (38 KB) read through
// L1/L2 (cache-resident). 1 row/lane, 4 rows/wave, 16 rows/block, 1024 blocks
// -> 4 blocks/CU, 4 waves/SIMD. ~80 VGPRs, no spill. Memory-bound by design.
// ---------------------------------------------------------------------------
__global__ __launch_bounds__(256) void main_kernel(const float* __restrict__ x,
                                                   const float* __restrict__ ws,
                                                   float* __restrict__ out) {
  const int tid  = threadIdx.x;
  const int wav  = tid >> 6;
  const int lane = tid & 63;
  const int kl   = lane & 15;
  const int row  = blockIdx.x * 16 + wav * 4 + (lane >> 4);
  const float* x0 = x + (size_t)row * DHID;

  float acc[11];
#pragma unroll
  for (int c = 0; c < 11; ++c) acc[c] = 0.f;

#pragma unroll 2
  for (int i = 0; i < 12; ++i) {
    const int d = 4 * kl + 64 * i;
    const float4 xv = *(const float4*)(x0 + d);
#pragma unroll
    for (int c = 0; c < 11; ++c) {
      const float4 mv = *(const float4*)(ws + c * MC_LD + d);
      acc[c] += xv.x * mv.x + xv.y * mv.y + xv.z * mv.z + xv.w * mv.w;
    }
  }
  if (kl < 4) {                              // tail: d = 768 + 4*kl < 784
    const int d = 768 + 4 * kl;
    const float4 xv = *(const float4*)(x0 + d);
#pragma unroll
    for (int c = 0; c < 11; ++c) {
      const float4 mv = *(const float4*)(ws + c * MC_LD + d);
      acc[c] += xv.x * mv.x + xv.y * mv.y + xv.z * mv.z + xv.w * mv.w;
    }
  }

  // reduce partial dots across the 16 k-lanes
#pragma unroll
  for (int c = 0; c < 11; ++c) {
    float v = acc[c];
    v += __shfl_xor(v, 1, 64);
    v += __shfl_xor(v, 2, 64);
    v += __shfl_xor(v, 4, 64);
    v += __shfl_xor(v, 8, 64);
    acc[c] = v;
  }

  // phasor tail: lane kl handles harmonics kl+1 and kl+17 (cos+sin each)
  const float m    = acc[10] + ws[C0_OFF + 10];
  const float base = DELTA0 * m;
  float s1, c1, s2, c2;
  __sincosf((float)(kl + 1)  * base, &s1, &c1);
  __sincosf((float)(kl + 17) * base, &s2, &c2);
  const float* m2a = ws + M2_OFF + (kl)      * M2_LD;   // cos, h=kl
  const float* m2b = ws + M2_OFF + (kl + 16) * M2_LD;   // cos, h=kl+16
  const float* m2c = ws + M2_OFF + (kl + 32) * M2_LD;   // sin, h=kl+32
  const float* m2d = ws + M2_OFF + (kl + 48) * M2_LD;   // sin, h=kl+48
  float t[10];
#pragma unroll
  for (int c = 0; c < 10; ++c)
    t[c] = c1 * m2a[c] + c2 * m2b[c] + s1 * m2c[c] + s2 * m2d[c];
#pragma unroll
  for (int c = 0; c < 10; ++c) {
    float v = t[c];
    v += __shfl_xor(v, 1, 64);
    v += __shfl_xor(v, 2, 64);
    v += __shfl_xor(v, 4, 64);
    v += __shfl_xor(v, 8, 64);
    t[c] = v;
  }
  if (kl == 0) {
#pragma unroll
    for (int c = 0; c < 10; ++c)
      out[row * NB + c] = acc[c] + t[c] + ws[C0_OFF + c];
  }
}

// ---------------------------------------------------------------------------
extern "C" void kernel_launch(void* const* d_in, const int* in_sizes, int n_in,
                              void* d_out, int out_size, void* d_ws, size_t ws_size,
                              hipStream_t stream) {
  const float* x     = (const float*)d_in[0];
  const float* W_in  = (const float*)d_in[1];
  const float* b_in  = (const float*)d_in[2];
  const float* W_ph  = (const float*)d_in[3];
  const float* b_ph  = (const float*)d_in[4];
  const float* W_out = (const float*)d_in[5];
  const float* b_out = (const float*)d_in[6];
  float* out = (float*)d_out;
  float* ws  = (float*)d_ws;

  prep_kernel<<<(DHID + 64 + 1 + 3) / 4, 256, 0, stream>>>(W_in, b_in, W_ph, b_ph,
                                                           W_out, b_out, ws);
  main_kernel<<<1024, 256, 0, stream>>>(x, ws, out);
}